// Round 8
// baseline (151.814 us; speedup 1.0000x reference)
//
#include <hip/hip_runtime.h>
#include <math.h>

// Multitask loss, two-kernel (atomic finish measured +60us: banned).
//   loss = mean(bce(pb,tb)) + mean(bce(pt,tt)) + mean(CE(ps,ts))
//        + mean((pb>0)^(pt[:,0]>0)) + mean((pb>0)^(argmax(ps)>0))
// bce(x,y) = max(x,0) - x*y + log1p(exp(-|x|))
//
// R8 theory: R2 is L1 line-request bound (~468 line-requests / 64 rows vs
// 116 minimum; ps 64B-lane-stride float4 = 64 lines/instr, pt/tt scalar =
// 20 lines/instr). Fix: stage ps/pt/tt through LDS with fully-coalesced
// float4 staging (requests -> ~117/64 rows), per-row compute reads LDS.
//  - ps LDS: XOR swizzle byte^=((row&7)<<4) on BOTH ds_write and read
//    (64B-stride b128 reads are 32-way conflicts unswizzled; with this
//    swizzle every aligned 8-lane group covers all 32 banks, both sides).
//  - pt/tt LDS reads: dword idx 5*t+j, gcd(5,32)=1 -> conflict-free.
//  - pb/tb/ts: direct global (already minimal-request, 12/64 rows).
//  - Single 26.6KB buffer -> 6 blocks/CU; next chunk's global loads issue
//    before current compute (T14 issue-early) for overlap.
// Fast intrinsics (__expf/__logf): tolerance 0.117 absmax on ~5.8 scalar.

#define NBLOCKS 2048
#define NTHREADS 256

#define PS_B 16384              // 256 rows * 64 B
#define PT_B 5120               // 256 rows * 20 B
#define LDS_BYTES (PS_B + 2 * PT_B)   // 26624

__device__ __forceinline__ float bce_term(float x, float y) {
    // max(x,0) - x*y + log1p(exp(-|x|)); log arg in (1,2] -> no cancellation
    return fmaxf(x, 0.0f) - x * y + __logf(1.0f + __expf(-fabsf(x)));
}

__device__ __forceinline__ float row_math(const float xs[16], float xb, float yb,
                                          int tg, float pt0, float bsum) {
    // argmax>0 <=> max(xs[1..15]) > xs[0] (strict, first-occurrence ties)
    float m15 = xs[1];
    #pragma unroll
    for (int j = 2; j < 16; ++j) m15 = fmaxf(m15, xs[j]);
    const float m = fmaxf(xs[0], m15);

    float se = 0.0f;
    float xt = 0.0f;  // xs[tg] via unrolled cndmask chain (no scratch)
    #pragma unroll
    for (int j = 0; j < 16; ++j) {
        se += __expf(xs[j] - m);
        xt = (j == tg) ? xs[j] : xt;
    }
    // task A
    float c = fmaxf(xb, 0.0f) - xb * yb + __logf(1.0f + __expf(-fabsf(xb)));
    // task C
    c += m + __logf(se) - xt;
    // task B (weight 1/5)
    c += bsum * 0.2f;
    // XOR consistency
    const bool bc = xb > 0.0f;
    c += (bc != (pt0 > 0.0f)) ? 1.0f : 0.0f;
    c += (bc != (m15 > xs[0])) ? 1.0f : 0.0f;
    return c;
}

__global__ __launch_bounds__(NTHREADS, 4) void mtl_partial_kernel(
    const float* __restrict__ pb,   // [B]    y_pred_binary
    const float* __restrict__ pt,   // [B,5]  y_pred_type
    const float* __restrict__ ps,   // [B,16] y_pred_source
    const float* __restrict__ tb,   // [B]    y_true_binary
    const float* __restrict__ tt,   // [B,5]  y_true_type
    const int*   __restrict__ ts,   // [B]    y_true_source
    double* __restrict__ partial,   // [NBLOCKS]
    int B)
{
    __shared__ __align__(16) unsigned char lds[LDS_BYTES];
    __shared__ double smem[NTHREADS / 64];

    const int t = threadIdx.x;
    float acc = 0.0f;   // 4 rows (~30 max each): f32 exact enough (absmax 0 so far)

    if (B == 4 * NBLOCKS * NTHREADS) {
        const float4* psf4 = reinterpret_cast<const float4*>(ps);
        const float4* ptf4 = reinterpret_cast<const float4*>(pt);
        const float4* ttf4 = reinterpret_cast<const float4*>(tt);

        float4 ps_r[4], pt_r[2], tt_r[2];

        // ---- prologue: stage chunk 0 into regs (coalesced float4) ----
        {
            const size_t R0 = (size_t)blockIdx.x * NTHREADS;
            const size_t psb = R0 * 4;          // f4 index
            const size_t ptb = (R0 / 4) * 5;    // f4 index (R0 % 4 == 0)
            #pragma unroll
            for (int q = 0; q < 4; ++q) ps_r[q] = psf4[psb + t + 256 * q];
            pt_r[0] = ptf4[ptb + t];
            tt_r[0] = ttf4[ptb + t];
            if (t < 64) {
                pt_r[1] = ptf4[ptb + 256 + t];
                tt_r[1] = ttf4[ptb + 256 + t];
            }
        }

        for (int k = 0; k < 4; ++k) {
            const size_t R0 = (size_t)k * NBLOCKS * NTHREADS
                            + (size_t)blockIdx.x * NTHREADS;

            __syncthreads();   // prior compute done reading lds
            // ---- ds_write staged regs (ps swizzled, pt/tt linear) ----
            #pragma unroll
            for (int q = 0; q < 4; ++q) {
                const int g   = t + 256 * q;               // f4 idx in ps region
                const int off = (g * 16) ^ (((g >> 2) & 7) << 4);
                *reinterpret_cast<float4*>(lds + off) = ps_r[q];
            }
            *reinterpret_cast<float4*>(lds + PS_B + t * 16)        = pt_r[0];
            *reinterpret_cast<float4*>(lds + PS_B + PT_B + t * 16) = tt_r[0];
            if (t < 64) {
                *reinterpret_cast<float4*>(lds + PS_B + (256 + t) * 16)        = pt_r[1];
                *reinterpret_cast<float4*>(lds + PS_B + PT_B + (256 + t) * 16) = tt_r[1];
            }
            __syncthreads();   // staged data visible

            // ---- issue next chunk's global loads BEFORE compute (T14) ----
            if (k < 3) {
                const size_t R1 = R0 + (size_t)NBLOCKS * NTHREADS;
                const size_t psb = R1 * 4;
                const size_t ptb = (R1 / 4) * 5;
                #pragma unroll
                for (int q = 0; q < 4; ++q) ps_r[q] = psf4[psb + t + 256 * q];
                pt_r[0] = ptf4[ptb + t];
                tt_r[0] = ttf4[ptb + t];
                if (t < 64) {
                    pt_r[1] = ptf4[ptb + 256 + t];
                    tt_r[1] = ttf4[ptb + 256 + t];
                }
            }

            // ---- compute this thread's row from LDS + direct scalars ----
            const size_t r = R0 + t;
            const float xb = pb[r];
            const float yb = tb[r];
            const int   tg = ts[r];

            float xs[16];  // static indexing only
            #pragma unroll
            for (int q = 0; q < 4; ++q) {
                const int off = (t * 64 + q * 16) ^ ((t & 7) << 4);
                const float4 v = *reinterpret_cast<const float4*>(lds + off);
                xs[q * 4 + 0] = v.x;
                xs[q * 4 + 1] = v.y;
                xs[q * 4 + 2] = v.z;
                xs[q * 4 + 3] = v.w;
            }
            const float* ldsf = reinterpret_cast<const float*>(lds);
            float bsum = 0.0f;
            float pt0  = 0.0f;
            #pragma unroll
            for (int j = 0; j < 5; ++j) {
                const float x = ldsf[(PS_B >> 2) + t * 5 + j];          // pt
                const float y = ldsf[((PS_B + PT_B) >> 2) + t * 5 + j]; // tt
                if (j == 0) pt0 = x;
                bsum += bce_term(x, y);
            }
            acc += row_math(xs, xb, yb, tg, pt0, bsum);
        }
    } else {
        // ---- generic fallback: R2-style direct loop ----
        const int stride = NBLOCKS * NTHREADS;
        for (int i = blockIdx.x * NTHREADS + t; i < B; i += stride) {
            const float xb = pb[i];
            const float yb = tb[i];
            const int   tg = ts[i];
            float xs[16];
            const float4* ps4 = reinterpret_cast<const float4*>(ps + (size_t)i * 16);
            #pragma unroll
            for (int q = 0; q < 4; ++q) {
                const float4 v = ps4[q];
                xs[q * 4 + 0] = v.x; xs[q * 4 + 1] = v.y;
                xs[q * 4 + 2] = v.z; xs[q * 4 + 3] = v.w;
            }
            float bsum = 0.0f, pt0 = 0.0f;
            #pragma unroll
            for (int j = 0; j < 5; ++j) {
                const float x = pt[(size_t)i * 5 + j];
                const float y = tt[(size_t)i * 5 + j];
                if (j == 0) pt0 = x;
                bsum += bce_term(x, y);
            }
            acc += row_math(xs, xb, yb, tg, pt0, bsum);
        }
        __syncthreads();  // keep barrier count uniform-safe (all threads reach)
    }

    // ---- block reduction (wave shfl in f32, cross-wave via LDS) ----
    float a = acc;
    #pragma unroll
    for (int off = 32; off > 0; off >>= 1)
        a += __shfl_down(a, off, 64);
    const int lane = t & 63;
    const int wave = t >> 6;
    if (lane == 0) smem[wave] = (double)a;
    __syncthreads();
    if (t == 0) {
        double s = 0.0;
        #pragma unroll
        for (int w = 0; w < NTHREADS / 64; ++w) s += smem[w];
        partial[blockIdx.x] = s;
    }
}

__global__ __launch_bounds__(NTHREADS) void mtl_final_kernel(
    const double* __restrict__ partial, float* __restrict__ out, int nblocks, int B)
{
    double acc = 0.0;
    for (int i = threadIdx.x; i < nblocks; i += NTHREADS)
        acc += partial[i];
    #pragma unroll
    for (int off = 32; off > 0; off >>= 1)
        acc += __shfl_down(acc, off, 64);
    __shared__ double smem[NTHREADS / 64];
    const int lane = threadIdx.x & 63;
    const int wave = threadIdx.x >> 6;
    if (lane == 0) smem[wave] = acc;
    __syncthreads();
    if (threadIdx.x == 0) {
        double s = 0.0;
        #pragma unroll
        for (int w = 0; w < NTHREADS / 64; ++w) s += smem[w];
        out[0] = (float)(s / (double)B);
    }
}

extern "C" void kernel_launch(void* const* d_in, const int* in_sizes, int n_in,
                              void* d_out, int out_size, void* d_ws, size_t ws_size,
                              hipStream_t stream) {
    const float* pb = (const float*)d_in[0];
    const float* pt = (const float*)d_in[1];
    const float* ps = (const float*)d_in[2];
    const float* tb = (const float*)d_in[3];
    const float* tt = (const float*)d_in[4];
    const int*   ts = (const int*)d_in[5];
    float* out = (float*)d_out;
    const int B = in_sizes[0];

    double* partial = (double*)d_ws;  // NBLOCKS doubles = 16 KiB

    mtl_partial_kernel<<<NBLOCKS, NTHREADS, 0, stream>>>(pb, pt, ps, tb, tt, ts, partial, B);
    mtl_final_kernel<<<1, NTHREADS, 0, stream>>>(partial, out, NBLOCKS, B);
}

// Round 9
// 49.431 us; speedup vs baseline: 3.0712x; 3.0712x over previous
//
#include <hip/hip_runtime.h>
#include <math.h>

// Multitask loss — R2 structure (measured best: direct loads, two kernels),
// refined grid: 8192 blocks x 256 thr = 1 row/thread (was 4 serial rows).
//   loss = mean(bce(pb,tb)) + mean(bce(pt,tt)) + mean(CE(ps,ts))
//        + mean((pb>0)^(pt[:,0]>0)) + mean((pb>0)^(argmax(ps)>0))
// bce(x,y) = max(x,0) - x*y + log1p(exp(-|x|))
//
// Measured dead-ends (do not revisit):
//  - LDS staging (R5: +62us barrier serialization; R8: +107us register-spill
//    round trip, WRITE_SIZE 270MB)
//  - single-kernel atomic finish (R5/R7: ~+60us, 2048 device-scope RMWs on
//    one line serialize as a tail)
//  - 4-consecutive-rows/thread dwordx4 (R4: FETCH +17%, lane spread worse)
//  - quad-cooperative softmax (R6: shuffle/divergence VALU ~ doubles)
// Fast intrinsics (__expf/__logf): tolerance 0.117 absmax on a ~5.8 scalar.

#define NTHREADS 256
#define MAXBLOCKS 8192

__device__ __forceinline__ float bce_term(float x, float y) {
    // max(x,0) - x*y + log1p(exp(-|x|)); log arg in (1,2] -> no cancellation
    return fmaxf(x, 0.0f) - x * y + __logf(1.0f + __expf(-fabsf(x)));
}

__global__ __launch_bounds__(NTHREADS) void mtl_partial_kernel(
    const float* __restrict__ pb,   // [B]    y_pred_binary
    const float* __restrict__ pt,   // [B,5]  y_pred_type
    const float* __restrict__ ps,   // [B,16] y_pred_source
    const float* __restrict__ tb,   // [B]    y_true_binary
    const float* __restrict__ tt,   // [B,5]  y_true_type
    const int*   __restrict__ ts,   // [B]    y_true_source
    double* __restrict__ partial,   // [gridDim.x]
    int B)
{
    const int stride = gridDim.x * NTHREADS;
    float acc = 0.0f;  // 1-4 rows (~30 max each): f32 exact (absmax 0 all rounds)

    for (int i = blockIdx.x * NTHREADS + threadIdx.x; i < B; i += stride) {
        const float xb = pb[i];
        const float yb = tb[i];
        const int   tg = ts[i];

        // task A
        float c = fmaxf(xb, 0.0f) - xb * yb + __logf(1.0f + __expf(-fabsf(xb)));

        // task B: 5 scalar dwords/row (R2 pattern, measured best)
        const float* ptr = pt + (size_t)i * 5;
        const float* ttr = tt + (size_t)i * 5;
        float t0 = 0.0f;
        float st = 0.0f;
        #pragma unroll
        for (int j = 0; j < 5; ++j) {
            const float x = ptr[j];
            const float y = ttr[j];
            if (j == 0) t0 = x;
            st += bce_term(x, y);
        }
        c += st * 0.2f;

        // task C: 16-way CE, 4x float4 (lane owns its 64B line)
        float xs[16];  // static indexing only
        const float4* ps4 = reinterpret_cast<const float4*>(ps + (size_t)i * 16);
        #pragma unroll
        for (int q = 0; q < 4; ++q) {
            const float4 v = ps4[q];
            xs[q * 4 + 0] = v.x;
            xs[q * 4 + 1] = v.y;
            xs[q * 4 + 2] = v.z;
            xs[q * 4 + 3] = v.w;
        }
        // argmax>0 <=> max(xs[1..15]) > xs[0] (strict, first-occurrence ties)
        float m15 = xs[1];
        #pragma unroll
        for (int j = 2; j < 16; ++j) m15 = fmaxf(m15, xs[j]);
        const float m = fmaxf(xs[0], m15);

        float se = 0.0f;
        float xt = 0.0f;  // xs[tg] via unrolled cndmask chain (no scratch)
        #pragma unroll
        for (int j = 0; j < 16; ++j) {
            se += __expf(xs[j] - m);
            xt = (j == tg) ? xs[j] : xt;
        }
        c += m + __logf(se) - xt;  // -logp[tg]

        // consistency XOR terms
        const bool bc = xb > 0.0f;
        c += (bc != (t0 > 0.0f)) ? 1.0f : 0.0f;
        c += (bc != (m15 > xs[0])) ? 1.0f : 0.0f;

        acc += c;
    }

    // ---- block reduction (wave shfl in f32, cross-wave via LDS) ----
    float a = acc;
    #pragma unroll
    for (int off = 32; off > 0; off >>= 1)
        a += __shfl_down(a, off, 64);

    __shared__ double smem[NTHREADS / 64];
    const int lane = threadIdx.x & 63;
    const int wave = threadIdx.x >> 6;
    if (lane == 0) smem[wave] = (double)a;
    __syncthreads();
    if (threadIdx.x == 0) {
        double s = 0.0;
        #pragma unroll
        for (int w = 0; w < NTHREADS / 64; ++w) s += smem[w];
        partial[blockIdx.x] = s;
    }
}

__global__ __launch_bounds__(NTHREADS) void mtl_final_kernel(
    const double* __restrict__ partial, float* __restrict__ out, int nblocks, int B)
{
    double acc = 0.0;
    for (int i = threadIdx.x; i < nblocks; i += NTHREADS)
        acc += partial[i];
    #pragma unroll
    for (int off = 32; off > 0; off >>= 1)
        acc += __shfl_down(acc, off, 64);
    __shared__ double smem[NTHREADS / 64];
    const int lane = threadIdx.x & 63;
    const int wave = threadIdx.x >> 6;
    if (lane == 0) smem[wave] = acc;
    __syncthreads();
    if (threadIdx.x == 0) {
        double s = 0.0;
        #pragma unroll
        for (int w = 0; w < NTHREADS / 64; ++w) s += smem[w];
        out[0] = (float)(s / (double)B);
    }
}

extern "C" void kernel_launch(void* const* d_in, const int* in_sizes, int n_in,
                              void* d_out, int out_size, void* d_ws, size_t ws_size,
                              hipStream_t stream) {
    const float* pb = (const float*)d_in[0];
    const float* pt = (const float*)d_in[1];
    const float* ps = (const float*)d_in[2];
    const float* tb = (const float*)d_in[3];
    const float* tt = (const float*)d_in[4];
    const int*   ts = (const int*)d_in[5];
    float* out = (float*)d_out;
    const int B = in_sizes[0];

    // 1 row/thread when possible (finer granularity -> better CU load balance
    // than R2's 4 serial rows at 2048 blocks); guard on workspace size.
    int nblocks = MAXBLOCKS;
    const int rows_cover = (B + NTHREADS - 1) / NTHREADS;
    if (nblocks > rows_cover) nblocks = rows_cover;          // don't overshoot B
    if ((size_t)nblocks * sizeof(double) > ws_size) nblocks = 2048;

    double* partial = (double*)d_ws;  // nblocks doubles (64 KiB at 8192)

    mtl_partial_kernel<<<nblocks, NTHREADS, 0, stream>>>(pb, pt, ps, tb, tt, ts, partial, B);
    mtl_final_kernel<<<1, NTHREADS, 0, stream>>>(partial, out, nblocks, B);
}

// Round 10
// 43.698 us; speedup vs baseline: 3.4742x; 1.1312x over previous
//
#include <hip/hip_runtime.h>
#include <math.h>

// Multitask loss — R2 structure (direct loads, 2048 blocks, two kernels) with
// CHUNKED ONLINE SOFTMAX to kill the per-row register spill.
//   loss = mean(bce(pb,tb)) + mean(bce(pt,tt)) + mean(CE(ps,ts))
//        + mean((pb>0)^(pt[:,0]>0)) + mean((pb>0)^(argmax(ps)>0))
// bce(x,y) = max(x,0) - x*y + log1p(exp(-|x|))
//
// Why: WRITE_SIZE scaled with thread count across R2/R7/R8/R9 at ~128 B/row
// -> xs[16] + temps spilled to scratch every row (VGPR squeezed to 32).
// Online-chunk softmax keeps <=14 floats live: per float4 chunk compute
// cmax + sum(exp(v-cmax)), then merge se = se*e^(m-m') + cs*e^(cm-m').
// Costs +6 exp/row; removes ~66 MB HBM scratch writes + reload latency.
//
// Measured dead-ends (do not revisit): LDS staging (R5/R8), atomic finish
// (R5/R7), 4-consecutive-rows dwordx4 (R4), quad-cooperative shuffles (R6),
// 8192 blocks (R9). Fast intrinsics ok: tolerance 0.117 on ~5.8 scalar.

#define NBLOCKS 2048
#define NTHREADS 256

__device__ __forceinline__ float bce_term(float x, float y) {
    // max(x,0) - x*y + log1p(exp(-|x|)); log arg in (1,2] -> no cancellation
    return fmaxf(x, 0.0f) - x * y + __logf(1.0f + __expf(-fabsf(x)));
}

__global__ __launch_bounds__(NTHREADS) void mtl_partial_kernel(
    const float* __restrict__ pb,   // [B]    y_pred_binary
    const float* __restrict__ pt,   // [B,5]  y_pred_type
    const float* __restrict__ ps,   // [B,16] y_pred_source
    const float* __restrict__ tb,   // [B]    y_true_binary
    const float* __restrict__ tt,   // [B,5]  y_true_type
    const int*   __restrict__ ts,   // [B]    y_true_source
    double* __restrict__ partial,   // [NBLOCKS]
    int B)
{
    const int stride = NBLOCKS * NTHREADS;
    float acc = 0.0f;  // 4 rows (~30 max each): f32 exact (absmax 0 all rounds)

    for (int i = blockIdx.x * NTHREADS + threadIdx.x; i < B; i += stride) {
        const float xb = pb[i];
        const float yb = tb[i];
        const int   tg = ts[i];

        // ---- task A ----
        float c = fmaxf(xb, 0.0f) - xb * yb + __logf(1.0f + __expf(-fabsf(xb)));

        // ---- task B: 5 scalar dwords/row, accumulate immediately ----
        const float* ptr = pt + (size_t)i * 5;
        const float* ttr = tt + (size_t)i * 5;
        float t0 = 0.0f;
        float st = 0.0f;
        #pragma unroll
        for (int j = 0; j < 5; ++j) {
            const float x = ptr[j];
            const float y = ttr[j];
            if (j == 0) t0 = x;
            st += bce_term(x, y);
        }
        c += st * 0.2f;

        // ---- task C: chunked online softmax (max 14 floats live) ----
        const float4* ps4 = reinterpret_cast<const float4*>(ps + (size_t)i * 16);
        float m, se, xt, m15, x0;
        {   // chunk 0
            const float4 v = ps4[0];
            x0 = v.x;
            const float cm_ex0 = fmaxf(fmaxf(v.y, v.z), v.w);
            m15 = cm_ex0;
            m   = fmaxf(v.x, cm_ex0);
            se  = __expf(v.x - m) + __expf(v.y - m) +
                  __expf(v.z - m) + __expf(v.w - m);
            const int k = tg & 3;
            const float sel = (k == 0) ? v.x : (k == 1) ? v.y
                            : (k == 2) ? v.z : v.w;
            xt = ((tg >> 2) == 0) ? sel : 0.0f;
        }
        #pragma unroll
        for (int q = 1; q < 4; ++q) {
            const float4 v = ps4[q];
            const float cm = fmaxf(fmaxf(v.x, v.y), fmaxf(v.z, v.w));
            const float cs = __expf(v.x - cm) + __expf(v.y - cm) +
                             __expf(v.z - cm) + __expf(v.w - cm);
            const float mn = fmaxf(m, cm);
            se = se * __expf(m - mn) + cs * __expf(cm - mn);
            m  = mn;
            m15 = fmaxf(m15, cm);
            const int k = tg & 3;
            const float sel = (k == 0) ? v.x : (k == 1) ? v.y
                            : (k == 2) ? v.z : v.w;
            xt = ((tg >> 2) == q) ? sel : xt;
        }
        c += m + __logf(se) - xt;  // -logp[tg]

        // ---- consistency XOR terms ----
        const bool bc = xb > 0.0f;
        c += (bc != (t0 > 0.0f)) ? 1.0f : 0.0f;
        c += (bc != (m15 > x0)) ? 1.0f : 0.0f;  // argmax>0, strict ties

        acc += c;
    }

    // ---- block reduction (wave shfl in f32, cross-wave via LDS) ----
    float a = acc;
    #pragma unroll
    for (int off = 32; off > 0; off >>= 1)
        a += __shfl_down(a, off, 64);

    __shared__ double smem[NTHREADS / 64];
    const int lane = threadIdx.x & 63;
    const int wave = threadIdx.x >> 6;
    if (lane == 0) smem[wave] = (double)a;
    __syncthreads();
    if (threadIdx.x == 0) {
        double s = 0.0;
        #pragma unroll
        for (int w = 0; w < NTHREADS / 64; ++w) s += smem[w];
        partial[blockIdx.x] = s;
    }
}

__global__ __launch_bounds__(NTHREADS) void mtl_final_kernel(
    const double* __restrict__ partial, float* __restrict__ out, int nblocks, int B)
{
    double acc = 0.0;
    for (int i = threadIdx.x; i < nblocks; i += NTHREADS)
        acc += partial[i];
    #pragma unroll
    for (int off = 32; off > 0; off >>= 1)
        acc += __shfl_down(acc, off, 64);
    __shared__ double smem[NTHREADS / 64];
    const int lane = threadIdx.x & 63;
    const int wave = threadIdx.x >> 6;
    if (lane == 0) smem[wave] = acc;
    __syncthreads();
    if (threadIdx.x == 0) {
        double s = 0.0;
        #pragma unroll
        for (int w = 0; w < NTHREADS / 64; ++w) s += smem[w];
        out[0] = (float)(s / (double)B);
    }
}

extern "C" void kernel_launch(void* const* d_in, const int* in_sizes, int n_in,
                              void* d_out, int out_size, void* d_ws, size_t ws_size,
                              hipStream_t stream) {
    const float* pb = (const float*)d_in[0];
    const float* pt = (const float*)d_in[1];
    const float* ps = (const float*)d_in[2];
    const float* tb = (const float*)d_in[3];
    const float* tt = (const float*)d_in[4];
    const int*   ts = (const int*)d_in[5];
    float* out = (float*)d_out;
    const int B = in_sizes[0];

    double* partial = (double*)d_ws;  // NBLOCKS doubles = 16 KiB

    mtl_partial_kernel<<<NBLOCKS, NTHREADS, 0, stream>>>(pb, pt, ps, tb, tt, ts, partial, B);
    mtl_final_kernel<<<1, NTHREADS, 0, stream>>>(partial, out, NBLOCKS, B);
}